// Round 1
// baseline (72.081 us; speedup 1.0000x reference)
//
#include <hip/hip_runtime.h>

#define SGRID 14
static constexpr float INV_S = 1.0f / 14.0f;

__global__ __launch_bounds__(256) void yolo_loss_kernel(
    const float* __restrict__ pred, const float* __restrict__ tgt,
    float* __restrict__ out, int ncells, float invN)
{
    int cell = blockIdx.x * blockDim.x + threadIdx.x;
    float loss = 0.0f;
    if (cell < ncells) {
        const float2* p2 = (const float2*)(pred + (size_t)cell * 30);
        const float2* t2 = (const float2*)(tgt  + (size_t)cell * 30);
        float p[30], t[30];
        #pragma unroll
        for (int j = 0; j < 15; ++j) { float2 v = p2[j]; p[2*j] = v.x; p[2*j+1] = v.y; }
        #pragma unroll
        for (int j = 0; j < 15; ++j) { float2 v = t2[j]; t[2*j] = v.x; t[2*j+1] = v.y; }

        float tconf = t[4];
        float obj   = (tconf == 1.0f) ? 1.0f : 0.0f;
        float noobj = (tconf == 0.0f) ? 1.0f : 0.0f;

        // no-object confidence loss (channels 4 and 9)
        float d4 = p[4] - t[4];
        float d9 = p[9] - t[9];
        float no_object_loss = noobj * (d4 * d4 + d9 * d9);

        // class loss over channels 10..29
        float class_loss = 0.0f;
        #pragma unroll
        for (int c = 10; c < 30; ++c) { float d = p[c] - t[c]; class_loss += d * d; }
        class_loss *= obj;

        // IoU for both boxes
        float iou[2];
        #pragma unroll
        for (int b = 0; b < 2; ++b) {
            int o = b * 5;
            float pcx = p[o] * INV_S, pcy = p[o+1] * INV_S, pw = p[o+2], ph = p[o+3];
            float tcx = t[o] * INV_S, tcy = t[o+1] * INV_S, tw = t[o+2], th = t[o+3];
            float px0 = pcx - 0.5f * pw, py0 = pcy - 0.5f * ph;
            float px1 = pcx + 0.5f * pw, py1 = pcy + 0.5f * ph;
            float tx0 = tcx - 0.5f * tw, ty0 = tcy - 0.5f * th;
            float tx1 = tcx + 0.5f * tw, ty1 = tcy + 0.5f * th;
            float lx = fmaxf(px0, tx0), ly = fmaxf(py0, ty0);
            float rx = fminf(px1, tx1), ry = fminf(py1, ty1);
            float wx = fmaxf(rx - lx, 0.0f), wy = fmaxf(ry - ly, 0.0f);
            float inter = wx * wy;
            float ap = (px1 - px0) * (py1 - py0);
            float at = (tx1 - tx0) * (ty1 - ty0);
            float denom = ap + at - inter;
            iou[b] = (denom > 0.0f) ? (inter / denom) : 0.0f;
        }

        // responsible box: box 1 wins ties
        bool pick1 = (iou[0] <= iou[1]);
        float chosen = pick1 ? iou[1] : iou[0];
        int o = pick1 ? 5 : 0;

        float dx = p[o]   - t[o];
        float dy = p[o+1] - t[o+1];
        float dw = sqrtf(p[o+2]) - sqrtf(t[o+2]);
        float dh = sqrtf(p[o+3]) - sqrtf(t[o+3]);
        float reg = dx * dx + dy * dy + dw * dw + dh * dh;

        float dconf = p[o+4] - chosen;
        float contain = dconf * dconf;

        loss = obj * (5.0f * reg + contain) + 0.5f * no_object_loss + class_loss;
    }

    // wave (64-lane) reduction
    #pragma unroll
    for (int off = 32; off > 0; off >>= 1) loss += __shfl_down(loss, off, 64);

    __shared__ float wsum[4];
    int lane = threadIdx.x & 63;
    int wv   = threadIdx.x >> 6;
    if (lane == 0) wsum[wv] = loss;
    __syncthreads();
    if (threadIdx.x == 0) {
        float s = (wsum[0] + wsum[1] + wsum[2] + wsum[3]) * invN;
        atomicAdd(out, s);
    }
}

extern "C" void kernel_launch(void* const* d_in, const int* in_sizes, int n_in,
                              void* d_out, int out_size, void* d_ws, size_t ws_size,
                              hipStream_t stream) {
    const float* pred = (const float*)d_in[0];
    const float* tgt  = (const float*)d_in[1];
    float* out = (float*)d_out;

    int ncells = in_sizes[0] / 30;                 // N * S * S
    int N      = ncells / (SGRID * SGRID);
    float invN = 1.0f / (float)N;

    hipMemsetAsync(out, 0, sizeof(float), stream);

    int threads = 256;
    int blocks  = (ncells + threads - 1) / threads;
    yolo_loss_kernel<<<blocks, threads, 0, stream>>>(pred, tgt, out, ncells, invN);
}

// Round 2
// 55.351 us; speedup vs baseline: 1.3023x; 1.3023x over previous
//
#include <hip/hip_runtime.h>

#define SGRID 14
static constexpr float INV_S = 1.0f / 14.0f;

// address-space-qualified pointer types for global_load_lds
typedef const unsigned int __attribute__((address_space(1)))* gas_ptr;
typedef unsigned int __attribute__((address_space(3)))* las_ptr;

__device__ __forceinline__ void gld_lds16(const void* g, void* l) {
    // async 16B/lane global -> LDS DMA; LDS dest = wave-uniform base + lane*16
    __builtin_amdgcn_global_load_lds((gas_ptr)g, (las_ptr)l, 16, 0, 0);
}

__device__ __forceinline__ float cell_loss(const float* p, const float* t) {
    float tconf = t[4];
    float obj   = (tconf == 1.0f) ? 1.0f : 0.0f;
    float noobj = (tconf == 0.0f) ? 1.0f : 0.0f;

    float d4 = p[4] - t[4];
    float d9 = p[9] - t[9];
    float no_object_loss = noobj * (d4 * d4 + d9 * d9);

    float class_loss = 0.0f;
    #pragma unroll
    for (int c = 10; c < 30; ++c) { float d = p[c] - t[c]; class_loss += d * d; }
    class_loss *= obj;

    float iou[2];
    #pragma unroll
    for (int b = 0; b < 2; ++b) {
        int o = b * 5;
        float pcx = p[o] * INV_S, pcy = p[o+1] * INV_S, pw = p[o+2], ph = p[o+3];
        float tcx = t[o] * INV_S, tcy = t[o+1] * INV_S, tw = t[o+2], th = t[o+3];
        float px0 = pcx - 0.5f * pw, py0 = pcy - 0.5f * ph;
        float px1 = pcx + 0.5f * pw, py1 = pcy + 0.5f * ph;
        float tx0 = tcx - 0.5f * tw, ty0 = tcy - 0.5f * th;
        float tx1 = tcx + 0.5f * tw, ty1 = tcy + 0.5f * th;
        float lx = fmaxf(px0, tx0), ly = fmaxf(py0, ty0);
        float rx = fminf(px1, tx1), ry = fminf(py1, ty1);
        float wx = fmaxf(rx - lx, 0.0f), wy = fmaxf(ry - ly, 0.0f);
        float inter = wx * wy;
        float ap = (px1 - px0) * (py1 - py0);
        float at = (tx1 - tx0) * (ty1 - ty0);
        float denom = ap + at - inter;
        iou[b] = (denom > 0.0f) ? (inter / denom) : 0.0f;
    }

    bool pick1 = (iou[0] <= iou[1]);
    float chosen = pick1 ? iou[1] : iou[0];
    int o = pick1 ? 5 : 0;

    float dx = p[o]   - t[o];
    float dy = p[o+1] - t[o+1];
    float dw = sqrtf(p[o+2]) - sqrtf(t[o+2]);
    float dh = sqrtf(p[o+3]) - sqrtf(t[o+3]);
    float reg = dx * dx + dy * dy + dw * dw + dh * dh;

    float dconf = p[o+4] - chosen;
    float contain = dconf * dconf;

    return obj * (5.0f * reg + contain) + 0.5f * no_object_loss + class_loss;
}

// One wave (64 threads) per block. Each chunk = 64 cells:
//   pred 64*30 floats (480 float4) + tgt 480 float4 = 960 float4 = 15 coalesced
//   1KB global_load_lds wave-instructions. Double-buffered, counted vmcnt.
__global__ __launch_bounds__(64) void yolo_loss_kernel(
    const float* __restrict__ pred, const float* __restrict__ tgt,
    float* __restrict__ out, int ncells, int nchunks, float invN)
{
    __shared__ float4 sbuf[2][960];   // 2 x 15360 B = 30720 B
    const int lane = threadIdx.x;     // 0..63
    float sum = 0.0f;

    int chunk  = blockIdx.x;
    const int stride = gridDim.x;
    int buf = 0;

    auto stage = [&](int c, int b) {
        const float4* p4 = (const float4*)(pred + (size_t)c * 1920);
        const float4* t4 = (const float4*)(tgt  + (size_t)c * 1920);
        #pragma unroll
        for (int j = 0; j < 15; ++j) {
            int f = j * 64 + lane;                               // 0..959
            const float4* g = (f < 480) ? (p4 + f) : (t4 + (f - 480));
            gld_lds16((const void*)g, (void*)&sbuf[b][j * 64]);  // uniform LDS base
        }
    };

    if (chunk < nchunks) stage(chunk, 0);

    while (chunk < nchunks) {
        int next = chunk + stride;
        if (next < nchunks) {
            // previous compute's ds_reads fully drained before overwriting buf^1
            asm volatile("s_waitcnt lgkmcnt(0)" ::: "memory");
            stage(next, buf ^ 1);
            // wait only for the CURRENT buffer's 15 DMAs (in-order completion)
            asm volatile("s_waitcnt vmcnt(15)" ::: "memory");
        } else {
            asm volatile("s_waitcnt vmcnt(0)" ::: "memory");
        }

        const float* base = (const float*)&sbuf[buf][0];
        const float2* cp2 = (const float2*)(base + lane * 30);
        const float2* ct2 = (const float2*)(base + 1920 + lane * 30);
        float p[30], t[30];
        #pragma unroll
        for (int j = 0; j < 15; ++j) { float2 v = cp2[j]; p[2*j] = v.x; p[2*j+1] = v.y; }
        #pragma unroll
        for (int j = 0; j < 15; ++j) { float2 v = ct2[j]; t[2*j] = v.x; t[2*j+1] = v.y; }

        sum += cell_loss(p, t);

        buf ^= 1;
        chunk = next;
    }

    // remainder cells (ncells % 64) — direct global path, block 0 only
    int rem = ncells - nchunks * 64;
    if (rem > 0 && blockIdx.x == 0 && lane < rem) {
        int cell = nchunks * 64 + lane;
        const float2* p2 = (const float2*)(pred + (size_t)cell * 30);
        const float2* t2 = (const float2*)(tgt  + (size_t)cell * 30);
        float p[30], t[30];
        #pragma unroll
        for (int j = 0; j < 15; ++j) { float2 v = p2[j]; p[2*j] = v.x; p[2*j+1] = v.y; }
        #pragma unroll
        for (int j = 0; j < 15; ++j) { float2 v = t2[j]; t[2*j] = v.x; t[2*j+1] = v.y; }
        sum += cell_loss(p, t);
    }

    #pragma unroll
    for (int off = 32; off > 0; off >>= 1) sum += __shfl_down(sum, off, 64);
    if (lane == 0) atomicAdd(out, sum * invN);
}

extern "C" void kernel_launch(void* const* d_in, const int* in_sizes, int n_in,
                              void* d_out, int out_size, void* d_ws, size_t ws_size,
                              hipStream_t stream) {
    const float* pred = (const float*)d_in[0];
    const float* tgt  = (const float*)d_in[1];
    float* out = (float*)d_out;

    int ncells  = in_sizes[0] / 30;               // N * S * S
    int N       = ncells / (SGRID * SGRID);
    float invN  = 1.0f / (float)N;
    int nchunks = ncells / 64;

    hipMemsetAsync(out, 0, sizeof(float) * (out_size > 0 ? out_size : 1), stream);

    int blocks = nchunks < 1 ? 1 : (nchunks < 1280 ? nchunks : 1280);
    yolo_loss_kernel<<<blocks, 64, 0, stream>>>(pred, tgt, out, ncells, nchunks, invN);
}